// Round 1
// baseline (124.343 us; speedup 1.0000x reference)
//
#include <hip/hip_runtime.h>

// Problem constants (from reference setup_inputs)
#define N_  8
#define K_  32
#define TK_ 128
#define TC_ 256
#define D_  512
#define TOUT_ (TK_ + TC_)          // 384
#define NEGINF_ (-1e20f)
#define INV_SQRT_D_ 0.044194173824159216f   // 1/sqrt(512)

// d_out layout (float):
//   full_enc : [N, TOUT, D]  -> 8*384*512 = 1572864
//   full_mask: [N, TOUT]     -> 3072
//   ck_attn  : [N, K]        -> 256
#define OUT_ENC_OFF_  0
#define OUT_MASK_OFF_ 1572864
#define OUT_ATTN_OFF_ 1575936

// ---------------------------------------------------------------
// Kernel 1: context pooling. grid = N, block = 256.
// ctx_use[n,d] = sum_t(mask * emb[tok,d]) / sqrt(cnt) * inv_sqrt_d
__global__ void pool_ctx_kernel(const int* __restrict__ src_tokens,
                                const float* __restrict__ emb,
                                float* __restrict__ ctx_use) {
    const int n = blockIdx.x;
    const int tid = threadIdx.x;
    __shared__ int s_tok[TC_];
    s_tok[tid] = src_tokens[n * TC_ + tid];
    __syncthreads();

    float a0 = 0.f, a1 = 0.f;
    int cnt = 0;
    #pragma unroll 4
    for (int t = 0; t < TC_; ++t) {
        const int tok = s_tok[t];
        if (tok != 0) {
            ++cnt;
            const float* row = emb + (size_t)tok * D_;
            a0 += row[tid];
            a1 += row[tid + 256];
        }
    }
    const float scale = INV_SQRT_D_ / sqrtf((float)cnt);
    ctx_use[(size_t)n * D_ + tid]       = a0 * scale;
    ctx_use[(size_t)n * D_ + tid + 256] = a1 * scale;
}

// ---------------------------------------------------------------
// Kernel 2: knowledge pooling. grid = N*K, block = 256.
__global__ void pool_know_kernel(const int* __restrict__ know_tokens,
                                 const float* __restrict__ emb,
                                 float* __restrict__ know_use) {
    const int b = blockIdx.x;          // n*K + k
    const int tid = threadIdx.x;
    __shared__ int s_tok[TK_];
    if (tid < TK_) s_tok[tid] = know_tokens[(size_t)b * TK_ + tid];
    __syncthreads();

    float a0 = 0.f, a1 = 0.f;
    int cnt = 0;
    #pragma unroll 4
    for (int t = 0; t < TK_; ++t) {
        const int tok = s_tok[t];
        if (tok != 0) {
            ++cnt;
            const float* row = emb + (size_t)tok * D_;
            a0 += row[tid];
            a1 += row[tid + 256];
        }
    }
    const float scale = INV_SQRT_D_ / sqrtf((float)cnt);
    know_use[(size_t)b * D_ + tid]       = a0 * scale;
    know_use[(size_t)b * D_ + tid + 256] = a1 * scale;
}

// ---------------------------------------------------------------
// Kernel 3: ck_attn = know_use . ctx_use, mask with NEGINF, argmax -> chosen.
// grid = N, block = 256 (4 waves; each wave handles 8 k's).
__global__ void attn_kernel(const float* __restrict__ ctx_use,
                            const float* __restrict__ know_use,
                            const int* __restrict__ ck_mask,
                            const int* __restrict__ cs_ids,
                            const int* __restrict__ use_cs_ids,
                            float* __restrict__ ck_attn_out,
                            int* __restrict__ chosen) {
    const int n = blockIdx.x;
    const int tid = threadIdx.x;
    const int wave = tid >> 6;
    const int lane = tid & 63;
    __shared__ float s_attn[K_];

    const float* cu = ctx_use + (size_t)n * D_;
    for (int kk = 0; kk < 8; ++kk) {
        const int k = wave * 8 + kk;
        const float* ku = know_use + ((size_t)n * K_ + k) * D_;
        float acc = 0.f;
        #pragma unroll
        for (int d = lane; d < D_; d += 64) acc += ku[d] * cu[d];
        #pragma unroll
        for (int off = 32; off > 0; off >>= 1) acc += __shfl_down(acc, off, 64);
        if (lane == 0) s_attn[k] = acc;
    }
    __syncthreads();

    if (tid < K_) {
        const float v = (ck_mask[n * K_ + tid] != 0) ? s_attn[tid] : NEGINF_;
        ck_attn_out[n * K_ + tid] = v;
        s_attn[tid] = v;
    }
    __syncthreads();

    if (tid == 0) {
        int best = 0;
        float bv = s_attn[0];
        for (int k = 1; k < K_; ++k) {
            if (s_attn[k] > bv) { bv = s_attn[k]; best = k; }   // first-max tie-break
        }
        chosen[n] = (use_cs_ids[0] != 0) ? cs_ids[n] : best;
    }
}

// ---------------------------------------------------------------
// Kernel 4: write full_enc [N,384,D] and full_mask [N,384].
// grid = N*TOUT, block = 128 (each thread copies one float4 of the emb row).
__global__ void gather_out_kernel(const int* __restrict__ src_tokens,
                                  const int* __restrict__ know_tokens,
                                  const int* __restrict__ chosen,
                                  const float* __restrict__ emb,
                                  float* __restrict__ full_enc,
                                  float* __restrict__ full_mask) {
    const int b = blockIdx.x;              // n*TOUT + r
    const int n = b / TOUT_;
    const int r = b - n * TOUT_;
    const int tid = threadIdx.x;           // 0..127

    int token;
    if (r < TK_) {
        token = know_tokens[((size_t)n * K_ + chosen[n]) * TK_ + r];
    } else {
        token = src_tokens[n * TC_ + (r - TK_)];
    }

    const float4* srow = (const float4*)(emb + (size_t)token * D_);
    float4* drow = (float4*)(full_enc + ((size_t)n * TOUT_ + r) * D_);
    drow[tid] = srow[tid];

    if (tid == 0) full_mask[n * TOUT_ + r] = (token != 0) ? 1.0f : 0.0f;
}

// ---------------------------------------------------------------
extern "C" void kernel_launch(void* const* d_in, const int* in_sizes, int n_in,
                              void* d_out, int out_size, void* d_ws, size_t ws_size,
                              hipStream_t stream) {
    const int*   src_tokens  = (const int*)d_in[0];   // [N,Tc]
    const int*   know_tokens = (const int*)d_in[1];   // [N,K,Tk]
    const int*   ck_mask     = (const int*)d_in[2];   // [N,K] 0/1
    const int*   cs_ids      = (const int*)d_in[3];   // [N]
    const int*   use_cs_ids  = (const int*)d_in[4];   // scalar
    const float* emb         = (const float*)d_in[5]; // [V,D]

    float* out = (float*)d_out;
    float* full_enc  = out + OUT_ENC_OFF_;
    float* full_mask = out + OUT_MASK_OFF_;
    float* ck_attn   = out + OUT_ATTN_OFF_;

    // workspace layout
    char* ws = (char*)d_ws;
    float* ctx_use  = (float*)ws;                               // N*D floats
    float* know_use = (float*)(ws + (size_t)N_ * D_ * 4);       // N*K*D floats
    int*   chosen   = (int*)(ws + (size_t)N_ * D_ * 4 + (size_t)N_ * K_ * D_ * 4); // N ints

    pool_ctx_kernel<<<N_, 256, 0, stream>>>(src_tokens, emb, ctx_use);
    pool_know_kernel<<<N_ * K_, 256, 0, stream>>>(know_tokens, emb, know_use);
    attn_kernel<<<N_, 256, 0, stream>>>(ctx_use, know_use, ck_mask, cs_ids,
                                        use_cs_ids, ck_attn, chosen);
    gather_out_kernel<<<N_ * TOUT_, 128, 0, stream>>>(src_tokens, know_tokens,
                                                      chosen, emb, full_enc, full_mask);
}

// Round 2
// 32.785 us; speedup vs baseline: 3.7926x; 3.7926x over previous
//
#include <hip/hip_runtime.h>

// Problem constants (from reference setup_inputs)
#define N_  8
#define K_  32
#define TK_ 128
#define TC_ 256
#define D_  512
#define TOUT_ (TK_ + TC_)          // 384
#define NEGINF_ (-1e20f)
#define INV_SQRT_D_ 0.044194173824159216f   // 1/sqrt(512)

// chunking for the partial-pool pass
#define CHUNK_ 32
#define CTX_CHUNKS_ (TC_ / CHUNK_)                 // 8
#define KNOW_CHUNKS_ (TK_ / CHUNK_)                // 4
#define CTX_BLOCKS_ (N_ * CTX_CHUNKS_)             // 64
#define KNOW_BLOCKS_ (N_ * K_ * KNOW_CHUNKS_)      // 1024
#define POOL_BLOCKS_ (CTX_BLOCKS_ + KNOW_BLOCKS_)  // 1088

// d_out layout (float):
//   full_enc : [N, TOUT, D]  -> 8*384*512 = 1572864
//   full_mask: [N, TOUT]     -> 3072
//   ck_attn  : [N, K]        -> 256
#define OUT_MASK_OFF_ 1572864
#define OUT_ATTN_OFF_ 1575936

// ---------------------------------------------------------------
// Kernel 1: partial pooling. grid = 1088 blocks, block = 256.
// Block bid < 64: ctx row n=bid/8, chunk bid%8.
// Block bid >= 64: know row b=(bid-64)/4, chunk (bid-64)%4.
// Each thread accumulates dims {2*tid, 2*tid+1} (one float2 per token).
__global__ void pool_partial_kernel(const int* __restrict__ src_tokens,
                                    const int* __restrict__ know_tokens,
                                    const float* __restrict__ emb,
                                    float2* __restrict__ partial,   // [1088, 256] float2
                                    int* __restrict__ pcounts) {    // [1088]
    const int bid = blockIdx.x;
    const int tid = threadIdx.x;
    __shared__ int s_tok[CHUNK_];

    const int* tokptr;
    if (bid < CTX_BLOCKS_) {
        const int n = bid >> 3, c = bid & 7;
        tokptr = src_tokens + n * TC_ + c * CHUNK_;
    } else {
        const int b = (bid - CTX_BLOCKS_) >> 2, c = (bid - CTX_BLOCKS_) & 3;
        tokptr = know_tokens + (size_t)b * TK_ + c * CHUNK_;
    }
    if (tid < CHUNK_) s_tok[tid] = tokptr[tid];
    __syncthreads();

    float a0 = 0.f, a1 = 0.f;
    int cnt = 0;
    #pragma unroll
    for (int t = 0; t < CHUNK_; ++t) {
        const int tok = s_tok[t];
        if (tok != 0) {
            ++cnt;
            const float2 v = ((const float2*)(emb + (size_t)tok * D_))[tid];
            a0 += v.x;
            a1 += v.y;
        }
    }
    partial[(size_t)bid * 256 + tid] = make_float2(a0, a1);
    if (tid == 0) pcounts[bid] = cnt;
}

// ---------------------------------------------------------------
// Kernel 2: reduce partials -> ctx_use [N,D], know_use [N*K,D].
// grid = 8 + 256 = 264 blocks, block = 256.
__global__ void pool_reduce_kernel(const float2* __restrict__ partial,
                                   const int* __restrict__ pcounts,
                                   float* __restrict__ ctx_use,
                                   float* __restrict__ know_use) {
    const int bid = blockIdx.x;
    const int tid = threadIdx.x;

    int base, nch;
    float* outp;
    if (bid < N_) {
        base = bid * CTX_CHUNKS_;
        nch = CTX_CHUNKS_;
        outp = ctx_use + (size_t)bid * D_;
    } else {
        base = CTX_BLOCKS_ + (bid - N_) * KNOW_CHUNKS_;
        nch = KNOW_CHUNKS_;
        outp = know_use + (size_t)(bid - N_) * D_;
    }

    float a0 = 0.f, a1 = 0.f;
    int cnt = 0;
    for (int c = 0; c < nch; ++c) {
        const float2 v = partial[(size_t)(base + c) * 256 + tid];
        a0 += v.x;
        a1 += v.y;
        cnt += pcounts[base + c];
    }
    const float scale = INV_SQRT_D_ / sqrtf((float)cnt);
    outp[2 * tid]     = a0 * scale;
    outp[2 * tid + 1] = a1 * scale;
}

// ---------------------------------------------------------------
// Kernel 3: ck_attn = know_use . ctx_use, mask with NEGINF, argmax -> chosen.
// grid = N, block = 256 (4 waves; each wave handles 8 k's).
__global__ void attn_kernel(const float* __restrict__ ctx_use,
                            const float* __restrict__ know_use,
                            const int* __restrict__ ck_mask,
                            const int* __restrict__ cs_ids,
                            const int* __restrict__ use_cs_ids,
                            float* __restrict__ ck_attn_out,
                            int* __restrict__ chosen) {
    const int n = blockIdx.x;
    const int tid = threadIdx.x;
    const int wave = tid >> 6;
    const int lane = tid & 63;
    __shared__ float s_attn[K_];

    const float* cu = ctx_use + (size_t)n * D_;
    for (int kk = 0; kk < 8; ++kk) {
        const int k = wave * 8 + kk;
        const float* ku = know_use + ((size_t)n * K_ + k) * D_;
        float acc = 0.f;
        #pragma unroll
        for (int d = lane; d < D_; d += 64) acc += ku[d] * cu[d];
        #pragma unroll
        for (int off = 32; off > 0; off >>= 1) acc += __shfl_down(acc, off, 64);
        if (lane == 0) s_attn[k] = acc;
    }
    __syncthreads();

    if (tid < K_) {
        const float v = (ck_mask[n * K_ + tid] != 0) ? s_attn[tid] : NEGINF_;
        ck_attn_out[n * K_ + tid] = v;
        s_attn[tid] = v;
    }
    __syncthreads();

    if (tid == 0) {
        int best = 0;
        float bv = s_attn[0];
        for (int k = 1; k < K_; ++k) {
            if (s_attn[k] > bv) { bv = s_attn[k]; best = k; }   // first-max tie-break
        }
        chosen[n] = (use_cs_ids[0] != 0) ? cs_ids[n] : best;
    }
}

// ---------------------------------------------------------------
// Kernel 4: write full_enc [N,384,D] and full_mask [N,384].
// grid = N*TOUT, block = 128 (each thread copies one float4 of the emb row).
__global__ void gather_out_kernel(const int* __restrict__ src_tokens,
                                  const int* __restrict__ know_tokens,
                                  const int* __restrict__ chosen,
                                  const float* __restrict__ emb,
                                  float* __restrict__ full_enc,
                                  float* __restrict__ full_mask) {
    const int b = blockIdx.x;              // n*TOUT + r
    const int n = b / TOUT_;
    const int r = b - n * TOUT_;
    const int tid = threadIdx.x;           // 0..127

    int token;
    if (r < TK_) {
        token = know_tokens[((size_t)n * K_ + chosen[n]) * TK_ + r];
    } else {
        token = src_tokens[n * TC_ + (r - TK_)];
    }

    const float4* srow = (const float4*)(emb + (size_t)token * D_);
    float4* drow = (float4*)(full_enc + ((size_t)n * TOUT_ + r) * D_);
    drow[tid] = srow[tid];

    if (tid == 0) full_mask[n * TOUT_ + r] = (token != 0) ? 1.0f : 0.0f;
}

// ---------------------------------------------------------------
extern "C" void kernel_launch(void* const* d_in, const int* in_sizes, int n_in,
                              void* d_out, int out_size, void* d_ws, size_t ws_size,
                              hipStream_t stream) {
    const int*   src_tokens  = (const int*)d_in[0];   // [N,Tc]
    const int*   know_tokens = (const int*)d_in[1];   // [N,K,Tk]
    const int*   ck_mask     = (const int*)d_in[2];   // [N,K] 0/1
    const int*   cs_ids      = (const int*)d_in[3];   // [N]
    const int*   use_cs_ids  = (const int*)d_in[4];   // scalar
    const float* emb         = (const float*)d_in[5]; // [V,D]

    float* out = (float*)d_out;
    float* full_enc  = out;
    float* full_mask = out + OUT_MASK_OFF_;
    float* ck_attn   = out + OUT_ATTN_OFF_;

    // workspace layout
    char* ws = (char*)d_ws;
    size_t off = 0;
    float2* partial = (float2*)(ws + off); off += (size_t)POOL_BLOCKS_ * 256 * sizeof(float2); // 2.23 MB
    int* pcounts    = (int*)(ws + off);   off += (size_t)POOL_BLOCKS_ * sizeof(int);
    off = (off + 255) & ~(size_t)255;
    float* ctx_use  = (float*)(ws + off); off += (size_t)N_ * D_ * sizeof(float);
    float* know_use = (float*)(ws + off); off += (size_t)N_ * K_ * D_ * sizeof(float);
    int* chosen     = (int*)(ws + off);

    pool_partial_kernel<<<POOL_BLOCKS_, 256, 0, stream>>>(src_tokens, know_tokens,
                                                          emb, partial, pcounts);
    pool_reduce_kernel<<<N_ + N_ * K_, 256, 0, stream>>>(partial, pcounts,
                                                         ctx_use, know_use);
    attn_kernel<<<N_, 256, 0, stream>>>(ctx_use, know_use, ck_mask, cs_ids,
                                        use_cs_ids, ck_attn, chosen);
    gather_out_kernel<<<N_ * TOUT_, 128, 0, stream>>>(src_tokens, know_tokens,
                                                      chosen, emb, full_enc, full_mask);
}

// Round 3
// 30.854 us; speedup vs baseline: 4.0300x; 1.0626x over previous
//
#include <hip/hip_runtime.h>

// Problem constants (from reference setup_inputs)
#define N_  8
#define K_  32
#define TK_ 128
#define TC_ 256
#define D_  512
#define D4_ (D_ / 4)               // 128 float4 per row
#define TOUT_ (TK_ + TC_)          // 384
#define NEGINF_ (-1e20f)
#define INV_SQRT_D_ 0.044194173824159216f   // 1/sqrt(512)

// d_out layout (float):
//   full_enc : [N, TOUT, D]  -> 1572864
//   full_mask: [N, TOUT]     -> 3072
//   ck_attn  : [N, K]        -> 256
#define OUT_MASK_OFF_ 1572864
#define OUT_ATTN_OFF_ 1575936

// Kernel-1 grid layout: [0,8) ctx-pool rows, [8,264) know-pool rows,
// [264, 264+128) ctx-copy blocks (16 output rows each).
#define POOL_ROWS_ (N_ + N_ * K_)             // 264
#define COPY_ROWS_ (N_ * TC_)                 // 2048 ctx rows of full_enc
#define COPY_BLOCKS_ (COPY_ROWS_ / 16)        // 128
#define K1_BLOCKS_ (POOL_ROWS_ + COPY_BLOCKS_)// 392

// ---------------------------------------------------------------
// Kernel 1: pooling (one block per row, 1024 thr, float4 gathers,
// LDS tree-reduce) + context portion of full_enc/full_mask.
__global__ __launch_bounds__(1024) void pool_kernel(
        const int* __restrict__ src_tokens,
        const int* __restrict__ know_tokens,
        const float* __restrict__ emb,
        float* __restrict__ ctx_use,     // [N,D]
        float* __restrict__ know_use,    // [N*K,D]
        float* __restrict__ full_enc,    // [N,TOUT,D]
        float* __restrict__ full_mask) { // [N,TOUT]
    const int bid = blockIdx.x;
    const int tid = threadIdx.x;
    const float4* emb4 = (const float4*)emb;

    if (bid >= POOL_ROWS_) {
        // ---- ctx-copy block: 16 rows of full_enc context region ----
        const int cb = bid - POOL_ROWS_;          // 0..127
        const int s = tid & 127;                   // float4 slot in row
        #pragma unroll
        for (int i = 0; i < 2; ++i) {
            const int g = cb * 16 + i * 8 + (tid >> 7);  // global ctx row 0..2047
            const int n = g >> 8;
            const int t = g & 255;
            const int tok = src_tokens[n * TC_ + t];
            float4* drow = (float4*)(full_enc + ((size_t)n * TOUT_ + TK_ + t) * D_);
            drow[s] = emb4[(size_t)tok * D4_ + s];
            if (s == 0) full_mask[n * TOUT_ + TK_ + t] = (tok != 0) ? 1.0f : 0.0f;
        }
        return;
    }

    // ---- pool block: one row (ctx n=bid if bid<8, else know b=bid-8) ----
    const int g = tid >> 7;        // token-group 0..7
    const int s = tid & 127;       // float4 dim-slot 0..127

    __shared__ int s_tok[TC_];
    __shared__ float4 s_red[8][D4_];   // 16 KB
    __shared__ int s_cnt[8];

    const int* tokptr;
    int T;
    float* outp;
    if (bid < N_) {
        tokptr = src_tokens + bid * TC_;  T = TC_;  outp = ctx_use + (size_t)bid * D_;
    } else {
        const int b = bid - N_;
        tokptr = know_tokens + (size_t)b * TK_;  T = TK_;  outp = know_use + (size_t)b * D_;
    }
    if (tid < T) s_tok[tid] = tokptr[tid];
    __syncthreads();

    float4 acc = make_float4(0.f, 0.f, 0.f, 0.f);
    int cnt = 0;
    #pragma unroll 8
    for (int t = g; t < T; t += 8) {
        const int tok = s_tok[t];
        if (tok != 0) {
            ++cnt;
            const float4 v = emb4[(size_t)tok * D4_ + s];
            acc.x += v.x; acc.y += v.y; acc.z += v.z; acc.w += v.w;
        }
    }
    s_red[g][s] = acc;
    if (s == 0) s_cnt[g] = cnt;
    __syncthreads();

    if (g == 0) {
        float4 tot = s_red[0][s];
        #pragma unroll
        for (int j = 1; j < 8; ++j) {
            const float4 v = s_red[j][s];
            tot.x += v.x; tot.y += v.y; tot.z += v.z; tot.w += v.w;
        }
        int c = 0;
        #pragma unroll
        for (int j = 0; j < 8; ++j) c += s_cnt[j];
        const float scale = INV_SQRT_D_ / sqrtf((float)c);
        tot.x *= scale; tot.y *= scale; tot.z *= scale; tot.w *= scale;
        ((float4*)outp)[s] = tot;
    }
}

// ---------------------------------------------------------------
// Kernel 2: ck_attn = know_use . ctx_use, mask, argmax -> chosen.
// grid = N, block = 256 (4 waves; each wave handles 8 k's).
__global__ void attn_kernel(const float* __restrict__ ctx_use,
                            const float* __restrict__ know_use,
                            const int* __restrict__ ck_mask,
                            const int* __restrict__ cs_ids,
                            const int* __restrict__ use_cs_ids,
                            float* __restrict__ ck_attn_out,
                            int* __restrict__ chosen) {
    const int n = blockIdx.x;
    const int tid = threadIdx.x;
    const int wave = tid >> 6;
    const int lane = tid & 63;
    __shared__ float s_attn[K_];

    const float4* cu4 = (const float4*)(ctx_use + (size_t)n * D_);
    const float4 c0 = cu4[lane];
    const float4 c1 = cu4[lane + 64];

    for (int kk = 0; kk < 8; ++kk) {
        const int k = wave * 8 + kk;
        const float4* ku4 = (const float4*)(know_use + ((size_t)n * K_ + k) * D_);
        const float4 a0 = ku4[lane];
        const float4 a1 = ku4[lane + 64];
        float acc = a0.x * c0.x + a0.y * c0.y + a0.z * c0.z + a0.w * c0.w
                  + a1.x * c1.x + a1.y * c1.y + a1.z * c1.z + a1.w * c1.w;
        #pragma unroll
        for (int off = 32; off > 0; off >>= 1) acc += __shfl_down(acc, off, 64);
        if (lane == 0) s_attn[k] = acc;
    }
    __syncthreads();

    if (tid < K_) {
        const float v = (ck_mask[n * K_ + tid] != 0) ? s_attn[tid] : NEGINF_;
        ck_attn_out[n * K_ + tid] = v;
        s_attn[tid] = v;
    }
    __syncthreads();

    if (tid == 0) {
        int best = 0;
        float bv = s_attn[0];
        for (int k = 1; k < K_; ++k) {
            if (s_attn[k] > bv) { bv = s_attn[k]; best = k; }   // first-max tie-break
        }
        chosen[n] = (use_cs_ids[0] != 0) ? cs_ids[n] : best;
    }
}

// ---------------------------------------------------------------
// Kernel 3: chosen-knowledge rows of full_enc/full_mask.
// grid = N*TK = 1024 blocks, block = 128 (one float4 per thread).
__global__ void gather_cs_kernel(const int* __restrict__ know_tokens,
                                 const int* __restrict__ chosen,
                                 const float* __restrict__ emb,
                                 float* __restrict__ full_enc,
                                 float* __restrict__ full_mask) {
    const int bid = blockIdx.x;
    const int n = bid >> 7;
    const int r = bid & 127;
    const int tid = threadIdx.x;

    const int token = know_tokens[((size_t)n * K_ + chosen[n]) * TK_ + r];
    const float4* srow = (const float4*)(emb + (size_t)token * D_);
    float4* drow = (float4*)(full_enc + ((size_t)n * TOUT_ + r) * D_);
    drow[tid] = srow[tid];

    if (tid == 0) full_mask[n * TOUT_ + r] = (token != 0) ? 1.0f : 0.0f;
}

// ---------------------------------------------------------------
extern "C" void kernel_launch(void* const* d_in, const int* in_sizes, int n_in,
                              void* d_out, int out_size, void* d_ws, size_t ws_size,
                              hipStream_t stream) {
    const int*   src_tokens  = (const int*)d_in[0];   // [N,Tc]
    const int*   know_tokens = (const int*)d_in[1];   // [N,K,Tk]
    const int*   ck_mask     = (const int*)d_in[2];   // [N,K] 0/1
    const int*   cs_ids      = (const int*)d_in[3];   // [N]
    const int*   use_cs_ids  = (const int*)d_in[4];   // scalar
    const float* emb         = (const float*)d_in[5]; // [V,D]

    float* out = (float*)d_out;
    float* full_enc  = out;
    float* full_mask = out + OUT_MASK_OFF_;
    float* ck_attn   = out + OUT_ATTN_OFF_;

    // workspace layout (tiny now)
    char* ws = (char*)d_ws;
    float* ctx_use  = (float*)ws;                                   // N*D
    float* know_use = ctx_use + (size_t)N_ * D_;                    // N*K*D
    int*   chosen   = (int*)(know_use + (size_t)N_ * K_ * D_);      // N

    pool_kernel<<<K1_BLOCKS_, 1024, 0, stream>>>(src_tokens, know_tokens, emb,
                                                 ctx_use, know_use,
                                                 full_enc, full_mask);
    attn_kernel<<<N_, 256, 0, stream>>>(ctx_use, know_use, ck_mask, cs_ids,
                                        use_cs_ids, ck_attn, chosen);
    gather_cs_kernel<<<N_ * TK_, 128, 0, stream>>>(know_tokens, chosen, emb,
                                                   full_enc, full_mask);
}